// Round 1
// baseline (2745.626 us; speedup 1.0000x reference)
//
#include <hip/hip_runtime.h>
#include <cstdint>
#include <cstddef>

#define HIDC   64
#define NGAUSS 50
#define NLAYER 3
#define TGRID  8192
#define CUTOFF_F 10.0f
#define LOG2_C 0.69314718055994530942f

__device__ __forceinline__ float sspf(float v) {
  // softplus(v) - log(2), numerically stable
  return fmaxf(v, 0.0f) + log1pf(expf(-fabsf(v))) - LOG2_C;
}

// ---------------------------------------------------------------------------
// Build per-layer lookup tables T_l(g, j) = [ssp(rbf(d)@w1+b1)@w2+b2]_j * C(d)
// for d on a uniform TGRID grid over [0, CUTOFF]. One 64-lane wave per point.
// ---------------------------------------------------------------------------
__global__ __launch_bounds__(64) void build_table_k(
    const float* __restrict__ mlp_w1, const float* __restrict__ mlp_b1,
    const float* __restrict__ mlp_w2, const float* __restrict__ mlp_b2,
    float* __restrict__ table) {
  int pid = blockIdx.x;              // l*TGRID + g
  int l = pid / TGRID;
  int g = pid - l * TGRID;
  int j = threadIdx.x;               // 0..63 output channel
  float d = (float)g * (CUTOFF_F / (float)(TGRID - 1));
  __shared__ float rbf_s[NGAUSS];
  __shared__ float hid_s[HIDC];
  const float delta = CUTOFF_F / (float)(NGAUSS - 1);
  const float coeff = -0.5f / (delta * delta);
  if (j < NGAUSS) {
    float t = d - (float)j * delta;
    rbf_s[j] = expf(coeff * t * t);
  }
  __syncthreads();
  const float* w1 = mlp_w1 + (size_t)l * NGAUSS * HIDC;
  float acc = mlp_b1[l * HIDC + j];
#pragma unroll
  for (int k = 0; k < NGAUSS; ++k) acc = fmaf(rbf_s[k], w1[k * HIDC + j], acc);
  hid_s[j] = sspf(acc);
  __syncthreads();
  const float* w2 = mlp_w2 + (size_t)l * HIDC * HIDC;
  float acc2 = mlp_b2[l * HIDC + j];
#pragma unroll
  for (int m = 0; m < HIDC; ++m) acc2 = fmaf(hid_s[m], w2[m * HIDC + j], acc2);
  float C = 0.5f * (cosf(d * (3.14159265358979323846f / CUTOFF_F)) + 1.0f);
  table[(size_t)pid * HIDC + j] = acc2 * C;
}

// ---------------------------------------------------------------------------
// Per-edge distance, pre-scaled to table-grid units.
// ---------------------------------------------------------------------------
__global__ __launch_bounds__(256) void edge_dist_k(
    const int* __restrict__ ei, const float* __restrict__ pos,
    float* __restrict__ u, int E) {
  int e = blockIdx.x * blockDim.x + threadIdx.x;
  if (e >= E) return;
  int s = ei[e], t = ei[E + e];
  float dx = pos[3 * s + 0] - pos[3 * t + 0];
  float dy = pos[3 * s + 1] - pos[3 * t + 1];
  float dz = pos[3 * s + 2] - pos[3 * t + 2];
  float d = sqrtf(fmaf(dx, dx, fmaf(dy, dy, dz * dz)));
  u[e] = d * ((float)(TGRID - 1) / CUTOFF_F);
}

// h = emb[z]
__global__ __launch_bounds__(256) void init_h_k(
    const int* __restrict__ z, const float* __restrict__ emb,
    float* __restrict__ h, int n64) {
  int i = blockIdx.x * blockDim.x + threadIdx.x;
  if (i >= n64) return;
  h[i] = emb[(z[i >> 6] << 6) | (i & 63)];
}

// x = h @ W   (64x64, no bias). One wave per node, lane = out channel.
__global__ __launch_bounds__(256) void node_lin_k(
    const float* __restrict__ h, const float* __restrict__ W,
    float* __restrict__ x, int n) {
  __shared__ float Ws[HIDC * HIDC];
  for (int i = threadIdx.x; i < HIDC * HIDC; i += 256) Ws[i] = W[i];
  __syncthreads();
  int j = threadIdx.x & 63;
  int gw = (blockIdx.x * 256 + threadIdx.x) >> 6;
  int nw = (gridDim.x * 256) >> 6;
  for (int node = gw; node < n; node += nw) {
    const float* hr = h + (size_t)node * HIDC;
    float acc = 0.0f;
#pragma unroll
    for (int k = 0; k < HIDC; ++k) acc = fmaf(hr[k], Ws[k * HIDC + j], acc);
    x[(size_t)node * HIDC + j] = acc;
  }
}

// The hot loop: per edge, lerp table row, gather x[src], scatter-add to agg[dst].
// One wave per edge; lane j = channel j.
__global__ __launch_bounds__(256) void edge_kernel_k(
    const int* __restrict__ esrc, const int* __restrict__ edst,
    const float* __restrict__ u, const float* __restrict__ table,
    const float* __restrict__ x, float* __restrict__ agg, int E) {
  int j = threadIdx.x & 63;
  int gw = (blockIdx.x * 256 + threadIdx.x) >> 6;
  int nw = (gridDim.x * 256) >> 6;
  int chunk = (E + nw - 1) / nw;
  int e0 = gw * chunk;
  int e1 = e0 + chunk; if (e1 > E) e1 = E;
  for (int e = e0; e < e1; ++e) {
    int eu = __builtin_amdgcn_readfirstlane(e);   // force scalar loads
    int s = esrc[eu];
    int t = edst[eu];
    float uu = u[eu];
    int i0 = (int)uu;
    if (i0 > TGRID - 2) i0 = TGRID - 2;
    float f = uu - (float)i0;
    const float* tp = table + (size_t)i0 * HIDC + j;
    float a = tp[0];
    float b = tp[HIDC];
    float w = fmaf(f, b - a, a);
    float xv = x[(size_t)s * HIDC + j];
    unsafeAtomicAdd(&agg[(size_t)t * HIDC + j], xv * w);
  }
}

// h += (ssp(agg @ W2 + b2)) @ W3 + b3. One wave per node.
__global__ __launch_bounds__(256) void node_update_k(
    const float* __restrict__ agg,
    const float* __restrict__ W2, const float* __restrict__ b2,
    const float* __restrict__ W3, const float* __restrict__ b3,
    float* __restrict__ h, int n) {
  __shared__ float W2s[HIDC * HIDC];
  __shared__ float W3s[HIDC * HIDC];
  for (int i = threadIdx.x; i < HIDC * HIDC; i += 256) {
    W2s[i] = W2[i];
    W3s[i] = W3[i];
  }
  __syncthreads();
  int j = threadIdx.x & 63;
  float bias2 = b2[j];
  float bias3 = b3[j];
  int gw = (blockIdx.x * 256 + threadIdx.x) >> 6;
  int nw = (gridDim.x * 256) >> 6;
  for (int node = gw; node < n; node += nw) {
    const float* ar = agg + (size_t)node * HIDC;
    float acc = bias2;
#pragma unroll
    for (int k = 0; k < HIDC; ++k) acc = fmaf(ar[k], W2s[k * HIDC + j], acc);
    float t = sspf(acc);
    float acc2 = bias3;
#pragma unroll
    for (int m = 0; m < HIDC; ++m) acc2 = fmaf(__shfl(t, m), W3s[m * HIDC + j], acc2);
    h[(size_t)node * HIDC + j] += acc2;
  }
}

// per-atom output MLP + segment-sum into per-molecule accumulator
__global__ __launch_bounds__(256) void out_kernel_k(
    const float* __restrict__ h, const int* __restrict__ batch,
    const float* __restrict__ ow1, const float* __restrict__ ob1,
    const float* __restrict__ ow2, const float* __restrict__ ob2,
    float* __restrict__ outg, int n) {
  __shared__ float W1s[HIDC * 32];
  __shared__ float w2s[32];
  for (int i = threadIdx.x; i < HIDC * 32; i += 256) W1s[i] = ow1[i];
  if (threadIdx.x < 32) w2s[threadIdx.x] = ow2[threadIdx.x];
  __syncthreads();
  int j = threadIdx.x & 63;
  int gw = (blockIdx.x * 256 + threadIdx.x) >> 6;
  int nw = (gridDim.x * 256) >> 6;
  float bias2 = ob2[0];
  for (int node = gw; node < n; node += nw) {
    const float* hr = h + (size_t)node * HIDC;
    float s = 0.0f;
    if (j < 32) {
      float acc = ob1[j];
#pragma unroll
      for (int k = 0; k < HIDC; ++k) acc = fmaf(hr[k], W1s[k * 32 + j], acc);
      s = sspf(acc) * w2s[j];
    }
#pragma unroll
    for (int off = 32; off > 0; off >>= 1) s += __shfl_down(s, off);
    if (j == 0) unsafeAtomicAdd(&outg[batch[node]], s + bias2);
  }
}

__global__ __launch_bounds__(256) void final_k(
    const float* __restrict__ outg, const float* __restrict__ fw,
    const float* __restrict__ fb, float* __restrict__ out, int g) {
  int i = blockIdx.x * blockDim.x + threadIdx.x;
  if (i < g) out[i] = fmaf(outg[i], fw[0], fb[0]);
}

extern "C" void kernel_launch(void* const* d_in, const int* in_sizes, int n_in,
                              void* d_out, int out_size, void* d_ws, size_t ws_size,
                              hipStream_t stream) {
  const int*   z      = (const int*)d_in[0];
  const float* pos    = (const float*)d_in[1];
  const int*   batch  = (const int*)d_in[2];
  const int*   ei     = (const int*)d_in[3];
  const float* emb    = (const float*)d_in[4];
  const float* out_w1 = (const float*)d_in[5];
  const float* out_b1 = (const float*)d_in[6];
  const float* out_w2 = (const float*)d_in[7];
  const float* out_b2 = (const float*)d_in[8];
  const float* fin_w  = (const float*)d_in[9];
  const float* fin_b  = (const float*)d_in[10];
  const float* mlp_w1 = (const float*)d_in[11];
  const float* mlp_b1 = (const float*)d_in[12];
  const float* mlp_w2 = (const float*)d_in[13];
  const float* mlp_b2 = (const float*)d_in[14];
  const float* cf1    = (const float*)d_in[15];
  const float* cf2    = (const float*)d_in[16];
  const float* cf2b   = (const float*)d_in[17];
  const float* intw   = (const float*)d_in[18];
  const float* intb   = (const float*)d_in[19];

  const int N = in_sizes[0];
  const int E = in_sizes[3] / 2;
  const int G = out_size;

  float* ws = (float*)d_ws;
  size_t off = 0;
  float* h    = ws + off; off += (size_t)N * HIDC;
  float* x    = ws + off; off += (size_t)N * HIDC;
  float* agg  = ws + off; off += (size_t)N * HIDC;
  float* u    = ws + off; off += (size_t)E;
  float* tab  = ws + off; off += (size_t)NLAYER * TGRID * HIDC;
  float* outg = ws + off; off += (size_t)G;

  build_table_k<<<dim3(NLAYER * TGRID), dim3(64), 0, stream>>>(
      mlp_w1, mlp_b1, mlp_w2, mlp_b2, tab);
  edge_dist_k<<<dim3((E + 255) / 256), dim3(256), 0, stream>>>(ei, pos, u, E);
  init_h_k<<<dim3((N * HIDC + 255) / 256), dim3(256), 0, stream>>>(z, emb, h, N * HIDC);
  hipMemsetAsync(outg, 0, (size_t)G * sizeof(float), stream);

  for (int l = 0; l < NLAYER; ++l) {
    hipMemsetAsync(agg, 0, (size_t)N * HIDC * sizeof(float), stream);
    node_lin_k<<<dim3(512), dim3(256), 0, stream>>>(
        h, cf1 + (size_t)l * HIDC * HIDC, x, N);
    edge_kernel_k<<<dim3(2048), dim3(256), 0, stream>>>(
        ei, ei + E, u, tab + (size_t)l * TGRID * HIDC, x, agg, E);
    node_update_k<<<dim3(512), dim3(256), 0, stream>>>(
        agg, cf2 + (size_t)l * HIDC * HIDC, cf2b + l * HIDC,
        intw + (size_t)l * HIDC * HIDC, intb + l * HIDC, h, N);
  }

  out_kernel_k<<<dim3(512), dim3(256), 0, stream>>>(
      h, batch, out_w1, out_b1, out_w2, out_b2, outg, N);
  final_k<<<dim3((G + 255) / 256), dim3(256), 0, stream>>>(
      outg, fin_w, fin_b, (float*)d_out, G);
}

// Round 2
// 2634.063 us; speedup vs baseline: 1.0424x; 1.0424x over previous
//
#include <hip/hip_runtime.h>
#include <cstdint>
#include <cstddef>

#define HIDC   64
#define NGAUSS 50
#define NLAYER 3
#define TGRID  8192
#define CUTOFF_F 10.0f
#define LOG2_C 0.69314718055994530942f

__device__ __forceinline__ float sspf(float v) {
  return fmaxf(v, 0.0f) + log1pf(expf(-fabsf(v))) - LOG2_C;
}

// ---------------------------------------------------------------------------
// Per-layer lookup tables T_l(g,j) = [ssp(rbf(d)@w1+b1)@w2+b2]_j * C(d)
// ---------------------------------------------------------------------------
__global__ __launch_bounds__(64) void build_table_k(
    const float* __restrict__ mlp_w1, const float* __restrict__ mlp_b1,
    const float* __restrict__ mlp_w2, const float* __restrict__ mlp_b2,
    float* __restrict__ table) {
  int pid = blockIdx.x;              // l*TGRID + g
  int l = pid / TGRID;
  int g = pid - l * TGRID;
  int j = threadIdx.x;
  float d = (float)g * (CUTOFF_F / (float)(TGRID - 1));
  __shared__ float rbf_s[NGAUSS];
  __shared__ float hid_s[HIDC];
  const float delta = CUTOFF_F / (float)(NGAUSS - 1);
  const float coeff = -0.5f / (delta * delta);
  if (j < NGAUSS) {
    float t = d - (float)j * delta;
    rbf_s[j] = expf(coeff * t * t);
  }
  __syncthreads();
  const float* w1 = mlp_w1 + (size_t)l * NGAUSS * HIDC;
  float acc = mlp_b1[l * HIDC + j];
#pragma unroll
  for (int k = 0; k < NGAUSS; ++k) acc = fmaf(rbf_s[k], w1[k * HIDC + j], acc);
  hid_s[j] = sspf(acc);
  __syncthreads();
  const float* w2 = mlp_w2 + (size_t)l * HIDC * HIDC;
  float acc2 = mlp_b2[l * HIDC + j];
#pragma unroll
  for (int m = 0; m < HIDC; ++m) acc2 = fmaf(hid_s[m], w2[m * HIDC + j], acc2);
  float C = 0.5f * (cosf(d * (3.14159265358979323846f / CUTOFF_F)) + 1.0f);
  table[(size_t)pid * HIDC + j] = acc2 * C;
}

// ---------------------------------------------------------------------------
// CSR build: histogram over dst
// ---------------------------------------------------------------------------
__global__ __launch_bounds__(256) void hist_k(
    const int* __restrict__ edst, int* __restrict__ deg, int E) {
  int e = blockIdx.x * blockDim.x + threadIdx.x;
  if (e < E) atomicAdd(&deg[edst[e]], 1);
}

// scanA: block-local inclusive scan of deg (1024 elems/block) into rs[1+i];
// block totals into bsum.
__global__ __launch_bounds__(256) void scanA_k(
    const int* __restrict__ deg, int* __restrict__ rs,
    int* __restrict__ bsum, int N) {
  __shared__ int sbuf[2][256];
  int tid = threadIdx.x;
  int base = blockIdx.x * 1024 + tid * 4;
  int v0 = (base + 0 < N) ? deg[base + 0] : 0;
  int v1 = (base + 1 < N) ? deg[base + 1] : 0;
  int v2 = (base + 2 < N) ? deg[base + 2] : 0;
  int v3 = (base + 3 < N) ? deg[base + 3] : 0;
  int p0 = v0, p1 = p0 + v1, p2 = p1 + v2, p3 = p2 + v3;
  int pout = 0;
  sbuf[0][tid] = p3;
  __syncthreads();
  for (int off = 1; off < 256; off <<= 1) {
    int pin = pout; pout ^= 1;
    int v = sbuf[pin][tid];
    if (tid >= off) v += sbuf[pin][tid - off];
    sbuf[pout][tid] = v;
    __syncthreads();
  }
  int texc = sbuf[pout][tid] - p3;
  if (base + 0 < N) rs[1 + base + 0] = texc + p0;
  if (base + 1 < N) rs[1 + base + 1] = texc + p1;
  if (base + 2 < N) rs[1 + base + 2] = texc + p2;
  if (base + 3 < N) rs[1 + base + 3] = texc + p3;
  if (tid == 255) bsum[blockIdx.x] = sbuf[pout][255];
}

__global__ void scanB_k(int* __restrict__ bsum, int nb) {
  if (threadIdx.x == 0 && blockIdx.x == 0) {
    int acc = 0;
    for (int i = 0; i < nb; ++i) { int v = bsum[i]; bsum[i] = acc; acc += v; }
  }
}

// scanC: finalize rs (global inclusive at rs[1+i]); cursor[i] = row start.
__global__ __launch_bounds__(256) void scanC_k(
    const int* __restrict__ bsum, const int* __restrict__ deg,
    int* __restrict__ rs, int* __restrict__ cursor, int N) {
  int i = blockIdx.x * blockDim.x + threadIdx.x;
  if (i < N) {
    int inc = rs[1 + i] + bsum[i >> 10];
    rs[1 + i] = inc;
    cursor[i] = inc - deg[i];
  }
  if (i == 0) rs[0] = 0;
}

// scatter: per edge compute d -> (i0, f), place (src,i0) + f at cursor[dst]++
__global__ __launch_bounds__(256) void scatter_k(
    const int* __restrict__ ei, const float* __restrict__ pos,
    int* __restrict__ cursor, int2* __restrict__ er,
    float* __restrict__ ef, int E) {
  int e = blockIdx.x * blockDim.x + threadIdx.x;
  if (e >= E) return;
  int s = ei[e], t = ei[E + e];
  float dx = pos[3 * s + 0] - pos[3 * t + 0];
  float dy = pos[3 * s + 1] - pos[3 * t + 1];
  float dz = pos[3 * s + 2] - pos[3 * t + 2];
  float d = sqrtf(fmaf(dx, dx, fmaf(dy, dy, dz * dz)));
  float u = d * ((float)(TGRID - 1) / CUTOFF_F);
  int i0 = (int)u;
  if (i0 > TGRID - 2) i0 = TGRID - 2;
  float f = u - (float)i0;
  int p = atomicAdd(&cursor[t], 1);
  er[p] = make_int2(s, i0);
  ef[p] = f;
}

// h = emb[z]
__global__ __launch_bounds__(256) void init_h_k(
    const int* __restrict__ z, const float* __restrict__ emb,
    float* __restrict__ h, int n64) {
  int i = blockIdx.x * blockDim.x + threadIdx.x;
  if (i >= n64) return;
  h[i] = emb[(z[i >> 6] << 6) | (i & 63)];
}

// x = h @ W (64x64, no bias). One wave per node, lane = out channel.
__global__ __launch_bounds__(256) void node_lin_k(
    const float* __restrict__ h, const float* __restrict__ W,
    float* __restrict__ x, int n) {
  __shared__ float Ws[HIDC * HIDC];
  for (int i = threadIdx.x; i < HIDC * HIDC; i += 256) Ws[i] = W[i];
  __syncthreads();
  int j = threadIdx.x & 63;
  int gw = (blockIdx.x * 256 + threadIdx.x) >> 6;
  int nw = (gridDim.x * 256) >> 6;
  for (int node = gw; node < n; node += nw) {
    const float* hr = h + (size_t)node * HIDC;
    float acc = 0.0f;
#pragma unroll
    for (int k = 0; k < HIDC; ++k) acc = fmaf(hr[k], Ws[k * HIDC + j], acc);
    x[(size_t)node * HIDC + j] = acc;
  }
}

// Fused: gather-aggregate over CSR row + cf_lin2 + ssp + int_lin + residual.
// One wave per dst node; lane j = channel j. No atomics, agg never hits memory.
__global__ __launch_bounds__(256) void node_gather_update_k(
    const int* __restrict__ rs, const int2* __restrict__ er,
    const float* __restrict__ ef, const float* __restrict__ table,
    const float* __restrict__ x,
    const float* __restrict__ W2, const float* __restrict__ b2,
    const float* __restrict__ W3, const float* __restrict__ b3,
    float* __restrict__ h, int n) {
  __shared__ float W2s[HIDC * HIDC];
  __shared__ float W3s[HIDC * HIDC];
  for (int i = threadIdx.x; i < HIDC * HIDC; i += 256) {
    W2s[i] = W2[i];
    W3s[i] = W3[i];
  }
  __syncthreads();
  int j = threadIdx.x & 63;
  float bias2 = b2[j];
  float bias3 = b3[j];
  int gw = (blockIdx.x * 256 + threadIdx.x) >> 6;
  int nw = (gridDim.x * 256) >> 6;
  for (int node = gw; node < n; node += nw) {
    int beg = __builtin_amdgcn_readfirstlane(rs[node]);
    int end = __builtin_amdgcn_readfirstlane(rs[node + 1]);
    float acc = 0.0f;
    for (int k = beg; k < end; ++k) {
      int2 rec = er[k];          // wave-uniform address -> broadcast
      float f = ef[k];
      const float* tp = table + (size_t)rec.y * HIDC + j;
      float a = tp[0];
      float b = tp[HIDC];
      float w = fmaf(f, b - a, a);
      acc = fmaf(x[(size_t)rec.x * HIDC + j], w, acc);
    }
    // acc across lanes = agg row. Apply cf_lin2 + ssp + int_lin + residual.
    float t_in = bias2;
#pragma unroll
    for (int m = 0; m < HIDC; ++m)
      t_in = fmaf(__shfl(acc, m), W2s[m * HIDC + j], t_in);
    float t = sspf(t_in);
    float o = bias3;
#pragma unroll
    for (int m = 0; m < HIDC; ++m)
      o = fmaf(__shfl(t, m), W3s[m * HIDC + j], o);
    h[(size_t)node * HIDC + j] += o;
  }
}

// per-atom output MLP + segment-sum into per-molecule accumulator
__global__ __launch_bounds__(256) void out_kernel_k(
    const float* __restrict__ h, const int* __restrict__ batch,
    const float* __restrict__ ow1, const float* __restrict__ ob1,
    const float* __restrict__ ow2, const float* __restrict__ ob2,
    float* __restrict__ outg, int n) {
  __shared__ float W1s[HIDC * 32];
  __shared__ float w2s[32];
  for (int i = threadIdx.x; i < HIDC * 32; i += 256) W1s[i] = ow1[i];
  if (threadIdx.x < 32) w2s[threadIdx.x] = ow2[threadIdx.x];
  __syncthreads();
  int j = threadIdx.x & 63;
  int gw = (blockIdx.x * 256 + threadIdx.x) >> 6;
  int nw = (gridDim.x * 256) >> 6;
  float bias2 = ob2[0];
  for (int node = gw; node < n; node += nw) {
    const float* hr = h + (size_t)node * HIDC;
    float s = 0.0f;
    if (j < 32) {
      float acc = ob1[j];
#pragma unroll
      for (int k = 0; k < HIDC; ++k) acc = fmaf(hr[k], W1s[k * 32 + j], acc);
      s = sspf(acc) * w2s[j];
    }
#pragma unroll
    for (int off = 32; off > 0; off >>= 1) s += __shfl_down(s, off);
    if (j == 0) unsafeAtomicAdd(&outg[batch[node]], s + bias2);
  }
}

__global__ __launch_bounds__(256) void final_k(
    const float* __restrict__ outg, const float* __restrict__ fw,
    const float* __restrict__ fb, float* __restrict__ out, int g) {
  int i = blockIdx.x * blockDim.x + threadIdx.x;
  if (i < g) out[i] = fmaf(outg[i], fw[0], fb[0]);
}

extern "C" void kernel_launch(void* const* d_in, const int* in_sizes, int n_in,
                              void* d_out, int out_size, void* d_ws, size_t ws_size,
                              hipStream_t stream) {
  const int*   z      = (const int*)d_in[0];
  const float* pos    = (const float*)d_in[1];
  const int*   batch  = (const int*)d_in[2];
  const int*   ei     = (const int*)d_in[3];
  const float* emb    = (const float*)d_in[4];
  const float* out_w1 = (const float*)d_in[5];
  const float* out_b1 = (const float*)d_in[6];
  const float* out_w2 = (const float*)d_in[7];
  const float* out_b2 = (const float*)d_in[8];
  const float* fin_w  = (const float*)d_in[9];
  const float* fin_b  = (const float*)d_in[10];
  const float* mlp_w1 = (const float*)d_in[11];
  const float* mlp_b1 = (const float*)d_in[12];
  const float* mlp_w2 = (const float*)d_in[13];
  const float* mlp_b2 = (const float*)d_in[14];
  const float* cf1    = (const float*)d_in[15];
  const float* cf2    = (const float*)d_in[16];
  const float* cf2b   = (const float*)d_in[17];
  const float* intw   = (const float*)d_in[18];
  const float* intb   = (const float*)d_in[19];

  const int N = in_sizes[0];
  const int E = in_sizes[3] / 2;
  const int G = out_size;
  const int NB = (N + 1023) / 1024;   // scan blocks

  char* wsb = (char*)d_ws;
  size_t off = 0;
  auto alloc = [&](size_t bytes) { char* p = wsb + off; off += (bytes + 255) & ~(size_t)255; return p; };
  float* h    = (float*)alloc((size_t)N * HIDC * sizeof(float));
  float* x    = (float*)alloc((size_t)N * HIDC * sizeof(float));
  float* tab  = (float*)alloc((size_t)NLAYER * TGRID * HIDC * sizeof(float));
  int2*  er   = (int2*)alloc((size_t)E * sizeof(int2));
  float* ef   = (float*)alloc((size_t)E * sizeof(float));
  int*   deg  = (int*)alloc((size_t)N * sizeof(int));
  int*   rs   = (int*)alloc((size_t)(N + 1) * sizeof(int));
  int*   cursor = (int*)alloc((size_t)N * sizeof(int));
  int*   bsum = (int*)alloc((size_t)NB * sizeof(int));
  float* outg = (float*)alloc((size_t)G * sizeof(float));

  // --- preprocessing (once; reused by all 3 layers) ---
  build_table_k<<<dim3(NLAYER * TGRID), dim3(64), 0, stream>>>(
      mlp_w1, mlp_b1, mlp_w2, mlp_b2, tab);
  hipMemsetAsync(deg, 0, (size_t)N * sizeof(int), stream);
  hipMemsetAsync(outg, 0, (size_t)G * sizeof(float), stream);
  hist_k<<<dim3((E + 255) / 256), dim3(256), 0, stream>>>(ei + E, deg, E);
  scanA_k<<<dim3(NB), dim3(256), 0, stream>>>(deg, rs, bsum, N);
  scanB_k<<<dim3(1), dim3(64), 0, stream>>>(bsum, NB);
  scanC_k<<<dim3((N + 255) / 256), dim3(256), 0, stream>>>(bsum, deg, rs, cursor, N);
  scatter_k<<<dim3((E + 255) / 256), dim3(256), 0, stream>>>(ei, pos, cursor, er, ef, E);
  init_h_k<<<dim3((N * HIDC + 255) / 256), dim3(256), 0, stream>>>(z, emb, h, N * HIDC);

  for (int l = 0; l < NLAYER; ++l) {
    node_lin_k<<<dim3(512), dim3(256), 0, stream>>>(
        h, cf1 + (size_t)l * HIDC * HIDC, x, N);
    node_gather_update_k<<<dim3(1024), dim3(256), 0, stream>>>(
        rs, er, ef, tab + (size_t)l * TGRID * HIDC, x,
        cf2 + (size_t)l * HIDC * HIDC, cf2b + l * HIDC,
        intw + (size_t)l * HIDC * HIDC, intb + l * HIDC, h, N);
  }

  out_kernel_k<<<dim3(512), dim3(256), 0, stream>>>(
      h, batch, out_w1, out_b1, out_w2, out_b2, outg, N);
  final_k<<<dim3((G + 255) / 256), dim3(256), 0, stream>>>(
      outg, fin_w, fin_b, (float*)d_out, G);
}

// Round 3
// 1545.371 us; speedup vs baseline: 1.7767x; 1.7045x over previous
//
#include <hip/hip_runtime.h>
#include <cstdint>
#include <cstddef>

#define HIDC   64
#define NGAUSS 50
#define NLAYER 3
#define TGRID  4096
#define CUTOFF_F 10.0f
#define LOG2_C 0.69314718055994530942f

__device__ __forceinline__ float sspf(float v) {
  return fmaxf(v, 0.0f) + log1pf(expf(-fabsf(v))) - LOG2_C;
}

// ---------------------------------------------------------------------------
// Per-layer lookup tables T_l(g,j) = [ssp(rbf(d)@w1+b1)@w2+b2]_j * C(d)
// ---------------------------------------------------------------------------
__global__ __launch_bounds__(64) void build_table_k(
    const float* __restrict__ mlp_w1, const float* __restrict__ mlp_b1,
    const float* __restrict__ mlp_w2, const float* __restrict__ mlp_b2,
    float* __restrict__ table) {
  int pid = blockIdx.x;              // l*TGRID + g
  int l = pid / TGRID;
  int g = pid - l * TGRID;
  int j = threadIdx.x;
  float d = (float)g * (CUTOFF_F / (float)(TGRID - 1));
  __shared__ float rbf_s[NGAUSS];
  __shared__ float hid_s[HIDC];
  const float delta = CUTOFF_F / (float)(NGAUSS - 1);
  const float coeff = -0.5f / (delta * delta);
  if (j < NGAUSS) {
    float t = d - (float)j * delta;
    rbf_s[j] = expf(coeff * t * t);
  }
  __syncthreads();
  const float* w1 = mlp_w1 + (size_t)l * NGAUSS * HIDC;
  float acc = mlp_b1[l * HIDC + j];
#pragma unroll
  for (int k = 0; k < NGAUSS; ++k) acc = fmaf(rbf_s[k], w1[k * HIDC + j], acc);
  hid_s[j] = sspf(acc);
  __syncthreads();
  const float* w2 = mlp_w2 + (size_t)l * HIDC * HIDC;
  float acc2 = mlp_b2[l * HIDC + j];
#pragma unroll
  for (int m = 0; m < HIDC; ++m) acc2 = fmaf(hid_s[m], w2[m * HIDC + j], acc2);
  float C = 0.5f * (cosf(d * (3.14159265358979323846f / CUTOFF_F)) + 1.0f);
  table[(size_t)pid * HIDC + j] = acc2 * C;
}

// ---------------------------------------------------------------------------
// CSR build
// ---------------------------------------------------------------------------
__global__ __launch_bounds__(256) void hist_k(
    const int* __restrict__ edst, int* __restrict__ deg, int E) {
  int e = blockIdx.x * blockDim.x + threadIdx.x;
  if (e < E) atomicAdd(&deg[edst[e]], 1);
}

__global__ __launch_bounds__(256) void scanA_k(
    const int* __restrict__ deg, int* __restrict__ rs,
    int* __restrict__ bsum, int N) {
  __shared__ int sbuf[2][256];
  int tid = threadIdx.x;
  int base = blockIdx.x * 1024 + tid * 4;
  int v0 = (base + 0 < N) ? deg[base + 0] : 0;
  int v1 = (base + 1 < N) ? deg[base + 1] : 0;
  int v2 = (base + 2 < N) ? deg[base + 2] : 0;
  int v3 = (base + 3 < N) ? deg[base + 3] : 0;
  int p0 = v0, p1 = p0 + v1, p2 = p1 + v2, p3 = p2 + v3;
  int pout = 0;
  sbuf[0][tid] = p3;
  __syncthreads();
  for (int off = 1; off < 256; off <<= 1) {
    int pin = pout; pout ^= 1;
    int v = sbuf[pin][tid];
    if (tid >= off) v += sbuf[pin][tid - off];
    sbuf[pout][tid] = v;
    __syncthreads();
  }
  int texc = sbuf[pout][tid] - p3;
  if (base + 0 < N) rs[1 + base + 0] = texc + p0;
  if (base + 1 < N) rs[1 + base + 1] = texc + p1;
  if (base + 2 < N) rs[1 + base + 2] = texc + p2;
  if (base + 3 < N) rs[1 + base + 3] = texc + p3;
  if (tid == 255) bsum[blockIdx.x] = sbuf[pout][255];
}

__global__ void scanB_k(int* __restrict__ bsum, int nb) {
  if (threadIdx.x == 0 && blockIdx.x == 0) {
    int acc = 0;
    for (int i = 0; i < nb; ++i) { int v = bsum[i]; bsum[i] = acc; acc += v; }
  }
}

__global__ __launch_bounds__(256) void scanC_k(
    const int* __restrict__ bsum, const int* __restrict__ deg,
    int* __restrict__ rs, int* __restrict__ cursor, int N) {
  int i = blockIdx.x * blockDim.x + threadIdx.x;
  if (i < N) {
    int inc = rs[1 + i] + bsum[i >> 10];
    rs[1 + i] = inc;
    cursor[i] = inc - deg[i];
  }
  if (i == 0) rs[0] = 0;
}

// per edge: d -> (i0, f). Pack (src, i0<<16|f_q16) at cursor[dst]++.
__global__ __launch_bounds__(256) void scatter_k(
    const int* __restrict__ ei, const float* __restrict__ pos,
    int* __restrict__ cursor, int2* __restrict__ er, int E) {
  int e = blockIdx.x * blockDim.x + threadIdx.x;
  if (e >= E) return;
  int s = ei[e], t = ei[E + e];
  float dx = pos[3 * s + 0] - pos[3 * t + 0];
  float dy = pos[3 * s + 1] - pos[3 * t + 1];
  float dz = pos[3 * s + 2] - pos[3 * t + 2];
  float d = sqrtf(fmaf(dx, dx, fmaf(dy, dy, dz * dz)));
  float u = d * ((float)(TGRID - 1) / CUTOFF_F);
  int i0 = (int)u;
  if (i0 > TGRID - 2) i0 = TGRID - 2;
  int fq = (int)((u - (float)i0) * 65536.0f);
  if (fq > 65535) fq = 65535;
  int p = atomicAdd(&cursor[t], 1);
  er[p] = make_int2(s, (i0 << 16) | fq);
}

// h = emb[z]
__global__ __launch_bounds__(256) void init_h_k(
    const int* __restrict__ z, const float* __restrict__ emb,
    float* __restrict__ h, int n64) {
  int i = blockIdx.x * blockDim.x + threadIdx.x;
  if (i >= n64) return;
  h[i] = emb[(z[i >> 6] << 6) | (i & 63)];
}

// x = h @ W (64x64, no bias). Persistent; one wave per node per step.
__global__ __launch_bounds__(256) void node_lin_k(
    const float* __restrict__ h, const float* __restrict__ W,
    float* __restrict__ x, int n) {
  __shared__ float Ws[HIDC * HIDC];
  for (int i = threadIdx.x; i < HIDC * HIDC; i += 256) Ws[i] = W[i];
  __syncthreads();
  int j = threadIdx.x & 63;
  int gw = (blockIdx.x * 256 + threadIdx.x) >> 6;
  int nw = (gridDim.x * 256) >> 6;
  for (int node = gw; node < n; node += nw) {
    float hv = h[((size_t)node << 6) + j];
    float acc = 0.0f;
#pragma unroll
    for (int k = 0; k < HIDC; ++k) acc = fmaf(__shfl(hv, k), Ws[k * HIDC + j], acc);
    x[((size_t)node << 6) + j] = acc;
  }
}

// THE HOT KERNEL. One wave per dst node, no LDS, edge loop unrolled x4
// (4 independent er->x/table chains in flight). agg written once per row.
__global__ __launch_bounds__(256) void gather_k(
    const int* __restrict__ rs, const int2* __restrict__ er,
    const float* __restrict__ table, const float* __restrict__ x,
    float* __restrict__ agg, int n) {
  int j = threadIdx.x & 63;
  int node = (blockIdx.x * 256 + threadIdx.x) >> 6;
  if (node >= n) return;
  int beg = __builtin_amdgcn_readfirstlane(rs[node]);
  int end = __builtin_amdgcn_readfirstlane(rs[node + 1]);
  float acc = 0.0f;
  int k = beg;
  for (; k + 4 <= end; k += 4) {
    int2 r0 = er[k + 0];
    int2 r1 = er[k + 1];
    int2 r2 = er[k + 2];
    int2 r3 = er[k + 3];
    const float* t0 = table + ((size_t)(r0.y >> 16) << 6) + j;
    const float* t1 = table + ((size_t)(r1.y >> 16) << 6) + j;
    const float* t2 = table + ((size_t)(r2.y >> 16) << 6) + j;
    const float* t3 = table + ((size_t)(r3.y >> 16) << 6) + j;
    float a0 = t0[0], c0 = t0[HIDC];
    float a1 = t1[0], c1 = t1[HIDC];
    float a2 = t2[0], c2 = t2[HIDC];
    float a3 = t3[0], c3 = t3[HIDC];
    float x0 = x[((size_t)r0.x << 6) + j];
    float x1 = x[((size_t)r1.x << 6) + j];
    float x2 = x[((size_t)r2.x << 6) + j];
    float x3 = x[((size_t)r3.x << 6) + j];
    float f0 = (float)(r0.y & 0xffff) * (1.0f / 65536.0f);
    float f1 = (float)(r1.y & 0xffff) * (1.0f / 65536.0f);
    float f2 = (float)(r2.y & 0xffff) * (1.0f / 65536.0f);
    float f3 = (float)(r3.y & 0xffff) * (1.0f / 65536.0f);
    acc = fmaf(x0, fmaf(f0, c0 - a0, a0), acc);
    acc = fmaf(x1, fmaf(f1, c1 - a1, a1), acc);
    acc = fmaf(x2, fmaf(f2, c2 - a2, a2), acc);
    acc = fmaf(x3, fmaf(f3, c3 - a3, a3), acc);
  }
  for (; k < end; ++k) {
    int2 r = er[k];
    const float* tp = table + ((size_t)(r.y >> 16) << 6) + j;
    float a = tp[0], c = tp[HIDC];
    float f = (float)(r.y & 0xffff) * (1.0f / 65536.0f);
    acc = fmaf(x[((size_t)r.x << 6) + j], fmaf(f, c - a, a), acc);
  }
  agg[((size_t)node << 6) + j] = acc;
}

// h += ssp(agg@W2+b2)@W3+b3. Persistent, LDS weights, shfl broadcast.
__global__ __launch_bounds__(256) void node_update_k(
    const float* __restrict__ agg,
    const float* __restrict__ W2, const float* __restrict__ b2,
    const float* __restrict__ W3, const float* __restrict__ b3,
    float* __restrict__ h, int n) {
  __shared__ float W2s[HIDC * HIDC];
  __shared__ float W3s[HIDC * HIDC];
  for (int i = threadIdx.x; i < HIDC * HIDC; i += 256) {
    W2s[i] = W2[i];
    W3s[i] = W3[i];
  }
  __syncthreads();
  int j = threadIdx.x & 63;
  float bias2 = b2[j];
  float bias3 = b3[j];
  int gw = (blockIdx.x * 256 + threadIdx.x) >> 6;
  int nw = (gridDim.x * 256) >> 6;
  for (int node = gw; node < n; node += nw) {
    float av = agg[((size_t)node << 6) + j];
    float t_in = bias2;
#pragma unroll
    for (int m = 0; m < HIDC; ++m)
      t_in = fmaf(__shfl(av, m), W2s[m * HIDC + j], t_in);
    float t = sspf(t_in);
    float o = bias3;
#pragma unroll
    for (int m = 0; m < HIDC; ++m)
      o = fmaf(__shfl(t, m), W3s[m * HIDC + j], o);
    h[((size_t)node << 6) + j] += o;
  }
}

// per-atom output MLP + per-molecule atomic reduce (uniform control flow)
__global__ __launch_bounds__(256) void out_kernel_k(
    const float* __restrict__ h, const int* __restrict__ batch,
    const float* __restrict__ ow1, const float* __restrict__ ob1,
    const float* __restrict__ ow2, const float* __restrict__ ob2,
    float* __restrict__ outg, int n) {
  __shared__ float W1s[HIDC * 32];
  __shared__ float w2s[32];
  for (int i = threadIdx.x; i < HIDC * 32; i += 256) W1s[i] = ow1[i];
  if (threadIdx.x < 32) w2s[threadIdx.x] = ow2[threadIdx.x];
  __syncthreads();
  int j = threadIdx.x & 63;
  int col = j & 31;
  int gw = (blockIdx.x * 256 + threadIdx.x) >> 6;
  int nw = (gridDim.x * 256) >> 6;
  float bias2 = ob2[0];
  for (int node = gw; node < n; node += nw) {
    float hv = h[((size_t)node << 6) + j];
    float acc = ob1[col];
#pragma unroll
    for (int k = 0; k < HIDC; ++k)
      acc = fmaf(__shfl(hv, k), W1s[k * 32 + col], acc);
    float s = sspf(acc) * w2s[col];   // each col computed twice (j and j+32)
#pragma unroll
    for (int off = 32; off > 0; off >>= 1) s += __shfl_down(s, off);
    if (j == 0) unsafeAtomicAdd(&outg[batch[node]], 0.5f * s + bias2);
  }
}

__global__ __launch_bounds__(256) void final_k(
    const float* __restrict__ outg, const float* __restrict__ fw,
    const float* __restrict__ fb, float* __restrict__ out, int g) {
  int i = blockIdx.x * blockDim.x + threadIdx.x;
  if (i < g) out[i] = fmaf(outg[i], fw[0], fb[0]);
}

extern "C" void kernel_launch(void* const* d_in, const int* in_sizes, int n_in,
                              void* d_out, int out_size, void* d_ws, size_t ws_size,
                              hipStream_t stream) {
  const int*   z      = (const int*)d_in[0];
  const float* pos    = (const float*)d_in[1];
  const int*   batch  = (const int*)d_in[2];
  const int*   ei     = (const int*)d_in[3];
  const float* emb    = (const float*)d_in[4];
  const float* out_w1 = (const float*)d_in[5];
  const float* out_b1 = (const float*)d_in[6];
  const float* out_w2 = (const float*)d_in[7];
  const float* out_b2 = (const float*)d_in[8];
  const float* fin_w  = (const float*)d_in[9];
  const float* fin_b  = (const float*)d_in[10];
  const float* mlp_w1 = (const float*)d_in[11];
  const float* mlp_b1 = (const float*)d_in[12];
  const float* mlp_w2 = (const float*)d_in[13];
  const float* mlp_b2 = (const float*)d_in[14];
  const float* cf1    = (const float*)d_in[15];
  const float* cf2    = (const float*)d_in[16];
  const float* cf2b   = (const float*)d_in[17];
  const float* intw   = (const float*)d_in[18];
  const float* intb   = (const float*)d_in[19];

  const int N = in_sizes[0];
  const int E = in_sizes[3] / 2;
  const int G = out_size;
  const int NB = (N + 1023) / 1024;

  char* wsb = (char*)d_ws;
  size_t off = 0;
  auto alloc = [&](size_t bytes) { char* p = wsb + off; off += (bytes + 255) & ~(size_t)255; return p; };
  float* h    = (float*)alloc((size_t)N * HIDC * sizeof(float));
  float* x    = (float*)alloc((size_t)N * HIDC * sizeof(float));
  float* agg  = (float*)alloc((size_t)N * HIDC * sizeof(float));
  float* tab  = (float*)alloc((size_t)NLAYER * TGRID * HIDC * sizeof(float));
  int2*  er   = (int2*)alloc((size_t)E * sizeof(int2));
  int*   rs   = (int*)alloc((size_t)(N + 1) * sizeof(int));
  float* outg = (float*)alloc((size_t)G * sizeof(float));
  // preprocessing-only arrays aliased into agg's region (agg is fully
  // rewritten by gather_k before its first read, after preprocessing ends)
  int* deg    = (int*)agg;
  int* cursor = (int*)agg + N;
  int* bsum   = (int*)agg + 2 * N;

  build_table_k<<<dim3(NLAYER * TGRID), dim3(64), 0, stream>>>(
      mlp_w1, mlp_b1, mlp_w2, mlp_b2, tab);
  hipMemsetAsync(deg, 0, (size_t)N * sizeof(int), stream);
  hipMemsetAsync(outg, 0, (size_t)G * sizeof(float), stream);
  hist_k<<<dim3((E + 255) / 256), dim3(256), 0, stream>>>(ei + E, deg, E);
  scanA_k<<<dim3(NB), dim3(256), 0, stream>>>(deg, rs, bsum, N);
  scanB_k<<<dim3(1), dim3(64), 0, stream>>>(bsum, NB);
  scanC_k<<<dim3((N + 255) / 256), dim3(256), 0, stream>>>(bsum, deg, rs, cursor, N);
  scatter_k<<<dim3((E + 255) / 256), dim3(256), 0, stream>>>(ei, pos, cursor, er, E);
  init_h_k<<<dim3((N * HIDC + 255) / 256), dim3(256), 0, stream>>>(z, emb, h, N * HIDC);

  const int gather_blocks = (N + 3) / 4;   // one wave per node
  for (int l = 0; l < NLAYER; ++l) {
    node_lin_k<<<dim3(2048), dim3(256), 0, stream>>>(
        h, cf1 + (size_t)l * HIDC * HIDC, x, N);
    gather_k<<<dim3(gather_blocks), dim3(256), 0, stream>>>(
        rs, er, tab + (size_t)l * TGRID * HIDC, x, agg, N);
    node_update_k<<<dim3(2048), dim3(256), 0, stream>>>(
        agg, cf2 + (size_t)l * HIDC * HIDC, cf2b + l * HIDC,
        intw + (size_t)l * HIDC * HIDC, intb + l * HIDC, h, N);
  }

  out_kernel_k<<<dim3(2048), dim3(256), 0, stream>>>(
      h, batch, out_w1, out_b1, out_w2, out_b2, outg, N);
  final_k<<<dim3((G + 255) / 256), dim3(256), 0, stream>>>(
      outg, fin_w, fin_b, (float*)d_out, G);
}

// Round 4
// 1241.532 us; speedup vs baseline: 2.2115x; 1.2447x over previous
//
#include <hip/hip_runtime.h>
#include <cstdint>
#include <cstddef>

#define HIDC   64
#define NGAUSS 50
#define NLAYER 3
#define TGRID  4096
#define CUTOFF_F 10.0f
#define LOG2_C 0.69314718055994530942f

__device__ __forceinline__ float sspf(float v) {
  return fmaxf(v, 0.0f) + log1pf(expf(-fabsf(v))) - LOG2_C;
}

// ---------------------------------------------------------------------------
// Per-layer lookup tables T_l(g,j) = [ssp(rbf(d)@w1+b1)@w2+b2]_j * C(d)
// ---------------------------------------------------------------------------
__global__ __launch_bounds__(64) void build_table_k(
    const float* __restrict__ mlp_w1, const float* __restrict__ mlp_b1,
    const float* __restrict__ mlp_w2, const float* __restrict__ mlp_b2,
    float* __restrict__ table) {
  int pid = blockIdx.x;              // l*TGRID + g
  int l = pid / TGRID;
  int g = pid - l * TGRID;
  int j = threadIdx.x;
  float d = (float)g * (CUTOFF_F / (float)(TGRID - 1));
  __shared__ float rbf_s[NGAUSS];
  __shared__ float hid_s[HIDC];
  const float delta = CUTOFF_F / (float)(NGAUSS - 1);
  const float coeff = -0.5f / (delta * delta);
  if (j < NGAUSS) {
    float t = d - (float)j * delta;
    rbf_s[j] = expf(coeff * t * t);
  }
  __syncthreads();
  const float* w1 = mlp_w1 + (size_t)l * NGAUSS * HIDC;
  float acc = mlp_b1[l * HIDC + j];
#pragma unroll
  for (int k = 0; k < NGAUSS; ++k) acc = fmaf(rbf_s[k], w1[k * HIDC + j], acc);
  hid_s[j] = sspf(acc);
  __syncthreads();
  const float* w2 = mlp_w2 + (size_t)l * HIDC * HIDC;
  float acc2 = mlp_b2[l * HIDC + j];
#pragma unroll
  for (int m = 0; m < HIDC; ++m) acc2 = fmaf(hid_s[m], w2[m * HIDC + j], acc2);
  float C = 0.5f * (cosf(d * (3.14159265358979323846f / CUTOFF_F)) + 1.0f);
  table[(size_t)pid * HIDC + j] = acc2 * C;
}

// tab2[l][g][j] = (T[g][j], T[g+1][j]) — both lerp endpoints in one 8B load
__global__ __launch_bounds__(256) void interleave_k(
    const float* __restrict__ tab, float2* __restrict__ tab2, int total) {
  int idx = blockIdx.x * blockDim.x + threadIdx.x;
  if (idx >= total) return;
  int rem = idx % (TGRID * HIDC);
  int g = rem / HIDC;
  float a = tab[idx];
  float c = (g < TGRID - 1) ? tab[idx + HIDC] : a;
  tab2[idx] = make_float2(a, c);
}

// ---------------------------------------------------------------------------
// CSR build
// ---------------------------------------------------------------------------
__global__ __launch_bounds__(256) void hist_k(
    const int* __restrict__ edst, int* __restrict__ deg, int E) {
  int e = blockIdx.x * blockDim.x + threadIdx.x;
  if (e < E) atomicAdd(&deg[edst[e]], 1);
}

__global__ __launch_bounds__(256) void scanA_k(
    const int* __restrict__ deg, int* __restrict__ rs,
    int* __restrict__ bsum, int N) {
  __shared__ int sbuf[2][256];
  int tid = threadIdx.x;
  int base = blockIdx.x * 1024 + tid * 4;
  int v0 = (base + 0 < N) ? deg[base + 0] : 0;
  int v1 = (base + 1 < N) ? deg[base + 1] : 0;
  int v2 = (base + 2 < N) ? deg[base + 2] : 0;
  int v3 = (base + 3 < N) ? deg[base + 3] : 0;
  int p0 = v0, p1 = p0 + v1, p2 = p1 + v2, p3 = p2 + v3;
  int pout = 0;
  sbuf[0][tid] = p3;
  __syncthreads();
  for (int off = 1; off < 256; off <<= 1) {
    int pin = pout; pout ^= 1;
    int v = sbuf[pin][tid];
    if (tid >= off) v += sbuf[pin][tid - off];
    sbuf[pout][tid] = v;
    __syncthreads();
  }
  int texc = sbuf[pout][tid] - p3;
  if (base + 0 < N) rs[1 + base + 0] = texc + p0;
  if (base + 1 < N) rs[1 + base + 1] = texc + p1;
  if (base + 2 < N) rs[1 + base + 2] = texc + p2;
  if (base + 3 < N) rs[1 + base + 3] = texc + p3;
  if (tid == 255) bsum[blockIdx.x] = sbuf[pout][255];
}

__global__ void scanB_k(int* __restrict__ bsum, int nb) {
  if (threadIdx.x == 0 && blockIdx.x == 0) {
    int acc = 0;
    for (int i = 0; i < nb; ++i) { int v = bsum[i]; bsum[i] = acc; acc += v; }
  }
}

__global__ __launch_bounds__(256) void scanC_k(
    const int* __restrict__ bsum, const int* __restrict__ deg,
    int* __restrict__ rs, int* __restrict__ cursor, int N) {
  int i = blockIdx.x * blockDim.x + threadIdx.x;
  if (i < N) {
    int inc = rs[1 + i] + bsum[i >> 10];
    rs[1 + i] = inc;
    cursor[i] = inc - deg[i];
  }
  if (i == 0) rs[0] = 0;
}

// per edge: d -> (i0, f). Pack (src, i0<<16|f_q16) at cursor[dst]++.
__global__ __launch_bounds__(256) void scatter_k(
    const int* __restrict__ ei, const float* __restrict__ pos,
    int* __restrict__ cursor, int2* __restrict__ er, int E) {
  int e = blockIdx.x * blockDim.x + threadIdx.x;
  if (e >= E) return;
  int s = ei[e], t = ei[E + e];
  float dx = pos[3 * s + 0] - pos[3 * t + 0];
  float dy = pos[3 * s + 1] - pos[3 * t + 1];
  float dz = pos[3 * s + 2] - pos[3 * t + 2];
  float d = sqrtf(fmaf(dx, dx, fmaf(dy, dy, dz * dz)));
  float u = d * ((float)(TGRID - 1) / CUTOFF_F);
  int i0 = (int)u;
  if (i0 > TGRID - 2) i0 = TGRID - 2;
  int fq = (int)((u - (float)i0) * 65536.0f);
  if (fq > 65535) fq = 65535;
  int p = atomicAdd(&cursor[t], 1);
  er[p] = make_int2(s, (i0 << 16) | fq);
}

// h = emb[z]
__global__ __launch_bounds__(256) void init_h_k(
    const int* __restrict__ z, const float* __restrict__ emb,
    float* __restrict__ h, int n64) {
  int i = blockIdx.x * blockDim.x + threadIdx.x;
  if (i >= n64) return;
  h[i] = emb[(z[i >> 6] << 6) | (i & 63)];
}

// ---------------------------------------------------------------------------
// Thread-per-node 64x64 GEMM building block: weights via wave-uniform
// addresses -> s_load (SGPR operand fma), row via per-thread float4.
// ---------------------------------------------------------------------------

// x = h @ W (no bias)
__global__ __launch_bounds__(256) void node_lin_k(
    const float* __restrict__ h, const float* __restrict__ W,
    float* __restrict__ x, int n) {
  int node = blockIdx.x * 256 + threadIdx.x;
  if (node >= n) return;
  const float* row = h + ((size_t)node << 6);
  float acc[HIDC];
#pragma unroll
  for (int j = 0; j < HIDC; ++j) acc[j] = 0.0f;
  for (int k = 0; k < HIDC; k += 4) {
    float4 rv = *(const float4*)(row + k);
    const float* w0 = W + (k + 0) * HIDC;
    const float* w1 = W + (k + 1) * HIDC;
    const float* w2 = W + (k + 2) * HIDC;
    const float* w3 = W + (k + 3) * HIDC;
#pragma unroll
    for (int j = 0; j < HIDC; ++j) {
      acc[j] = fmaf(rv.x, w0[j], acc[j]);
      acc[j] = fmaf(rv.y, w1[j], acc[j]);
      acc[j] = fmaf(rv.z, w2[j], acc[j]);
      acc[j] = fmaf(rv.w, w3[j], acc[j]);
    }
  }
  float* xr = x + ((size_t)node << 6);
#pragma unroll
  for (int j = 0; j < HIDC; j += 4) {
    float4 o = make_float4(acc[j], acc[j + 1], acc[j + 2], acc[j + 3]);
    *(float4*)(xr + j) = o;
  }
}

// t = ssp(agg @ W2 + b2)
__global__ __launch_bounds__(256) void update1_k(
    const float* __restrict__ agg, const float* __restrict__ W2,
    const float* __restrict__ b2, float* __restrict__ t, int n) {
  int node = blockIdx.x * 256 + threadIdx.x;
  if (node >= n) return;
  const float* row = agg + ((size_t)node << 6);
  float acc[HIDC];
#pragma unroll
  for (int j = 0; j < HIDC; ++j) acc[j] = b2[j];
  for (int k = 0; k < HIDC; k += 4) {
    float4 rv = *(const float4*)(row + k);
    const float* w0 = W2 + (k + 0) * HIDC;
    const float* w1 = W2 + (k + 1) * HIDC;
    const float* w2 = W2 + (k + 2) * HIDC;
    const float* w3 = W2 + (k + 3) * HIDC;
#pragma unroll
    for (int j = 0; j < HIDC; ++j) {
      acc[j] = fmaf(rv.x, w0[j], acc[j]);
      acc[j] = fmaf(rv.y, w1[j], acc[j]);
      acc[j] = fmaf(rv.z, w2[j], acc[j]);
      acc[j] = fmaf(rv.w, w3[j], acc[j]);
    }
  }
  float* tr = t + ((size_t)node << 6);
#pragma unroll
  for (int j = 0; j < HIDC; j += 4) {
    float4 o = make_float4(sspf(acc[j]), sspf(acc[j + 1]),
                           sspf(acc[j + 2]), sspf(acc[j + 3]));
    *(float4*)(tr + j) = o;
  }
}

// h += t @ W3 + b3
__global__ __launch_bounds__(256) void update2_k(
    const float* __restrict__ t, const float* __restrict__ W3,
    const float* __restrict__ b3, float* __restrict__ h, int n) {
  int node = blockIdx.x * 256 + threadIdx.x;
  if (node >= n) return;
  const float* row = t + ((size_t)node << 6);
  float acc[HIDC];
#pragma unroll
  for (int j = 0; j < HIDC; ++j) acc[j] = b3[j];
  for (int k = 0; k < HIDC; k += 4) {
    float4 rv = *(const float4*)(row + k);
    const float* w0 = W3 + (k + 0) * HIDC;
    const float* w1 = W3 + (k + 1) * HIDC;
    const float* w2 = W3 + (k + 2) * HIDC;
    const float* w3 = W3 + (k + 3) * HIDC;
#pragma unroll
    for (int j = 0; j < HIDC; ++j) {
      acc[j] = fmaf(rv.x, w0[j], acc[j]);
      acc[j] = fmaf(rv.y, w1[j], acc[j]);
      acc[j] = fmaf(rv.z, w2[j], acc[j]);
      acc[j] = fmaf(rv.w, w3[j], acc[j]);
    }
  }
  float* hr = h + ((size_t)node << 6);
#pragma unroll
  for (int j = 0; j < HIDC; j += 4) {
    float4 hv = *(float4*)(hr + j);
    hv.x += acc[j]; hv.y += acc[j + 1]; hv.z += acc[j + 2]; hv.w += acc[j + 3];
    *(float4*)(hr + j) = hv;
  }
}

// THE HOT KERNEL. One wave per dst node, edge loop unrolled x4.
__global__ __launch_bounds__(256) void gather_k(
    const int* __restrict__ rs, const int2* __restrict__ er,
    const float2* __restrict__ tab2, const float* __restrict__ x,
    float* __restrict__ agg, int n) {
  int j = threadIdx.x & 63;
  int node = (blockIdx.x * 256 + threadIdx.x) >> 6;
  if (node >= n) return;
  int beg = __builtin_amdgcn_readfirstlane(rs[node]);
  int end = __builtin_amdgcn_readfirstlane(rs[node + 1]);
  float acc = 0.0f;
  int k = beg;
  for (; k + 4 <= end; k += 4) {
    int2 r0 = er[k + 0];
    int2 r1 = er[k + 1];
    int2 r2 = er[k + 2];
    int2 r3 = er[k + 3];
    float2 ac0 = tab2[((size_t)(r0.y >> 16) << 6) + j];
    float2 ac1 = tab2[((size_t)(r1.y >> 16) << 6) + j];
    float2 ac2 = tab2[((size_t)(r2.y >> 16) << 6) + j];
    float2 ac3 = tab2[((size_t)(r3.y >> 16) << 6) + j];
    float x0 = x[((size_t)r0.x << 6) + j];
    float x1 = x[((size_t)r1.x << 6) + j];
    float x2 = x[((size_t)r2.x << 6) + j];
    float x3 = x[((size_t)r3.x << 6) + j];
    float f0 = (float)(r0.y & 0xffff) * (1.0f / 65536.0f);
    float f1 = (float)(r1.y & 0xffff) * (1.0f / 65536.0f);
    float f2 = (float)(r2.y & 0xffff) * (1.0f / 65536.0f);
    float f3 = (float)(r3.y & 0xffff) * (1.0f / 65536.0f);
    acc = fmaf(x0, fmaf(f0, ac0.y - ac0.x, ac0.x), acc);
    acc = fmaf(x1, fmaf(f1, ac1.y - ac1.x, ac1.x), acc);
    acc = fmaf(x2, fmaf(f2, ac2.y - ac2.x, ac2.x), acc);
    acc = fmaf(x3, fmaf(f3, ac3.y - ac3.x, ac3.x), acc);
  }
  for (; k < end; ++k) {
    int2 r = er[k];
    float2 ac = tab2[((size_t)(r.y >> 16) << 6) + j];
    float f = (float)(r.y & 0xffff) * (1.0f / 65536.0f);
    acc = fmaf(x[((size_t)r.x << 6) + j], fmaf(f, ac.y - ac.x, ac.x), acc);
  }
  agg[((size_t)node << 6) + j] = acc;
}

// per-atom output MLP + segmented wave reduce (batch sorted) + atomic
__global__ __launch_bounds__(256) void out_kernel_k(
    const float* __restrict__ h, const int* __restrict__ batch,
    const float* __restrict__ ow1, const float* __restrict__ ob1,
    const float* __restrict__ ow2, const float* __restrict__ ob2,
    float* __restrict__ outg, int n) {
  int node = blockIdx.x * 256 + threadIdx.x;
  int lane = threadIdx.x & 63;
  bool valid = node < n;
  int b = batch[valid ? node : (n - 1)];
  float s = 0.0f;
  if (valid) {
    const float* row = h + ((size_t)node << 6);
    float acc[32];
#pragma unroll
    for (int j = 0; j < 32; ++j) acc[j] = ob1[j];
    for (int k = 0; k < HIDC; k += 4) {
      float4 rv = *(const float4*)(row + k);
      const float* w0 = ow1 + (k + 0) * 32;
      const float* w1 = ow1 + (k + 1) * 32;
      const float* w2 = ow1 + (k + 2) * 32;
      const float* w3 = ow1 + (k + 3) * 32;
#pragma unroll
      for (int j = 0; j < 32; ++j) {
        acc[j] = fmaf(rv.x, w0[j], acc[j]);
        acc[j] = fmaf(rv.y, w1[j], acc[j]);
        acc[j] = fmaf(rv.z, w2[j], acc[j]);
        acc[j] = fmaf(rv.w, w3[j], acc[j]);
      }
    }
    s = ob2[0];
#pragma unroll
    for (int j = 0; j < 32; ++j) s = fmaf(sspf(acc[j]), ow2[j], s);
  }
  // segmented suffix sum over contiguous equal-b runs (batch sorted)
#pragma unroll
  for (int off = 1; off < 64; off <<= 1) {
    float so = __shfl_down(s, off);
    int bo = __shfl_down(b, off);
    if (lane + off < 64 && bo == b) s += so;
  }
  int bprev = __shfl_up(b, 1);
  bool head = (lane == 0) || (bprev != b);
  if (head && valid) unsafeAtomicAdd(&outg[b], s);
  // note: invalid lanes have s=0 and b of last node; if merged into a real
  // run they contribute 0; if head they'd add 0 but are guarded by valid.
  // A head lane whose run contains invalid tail lanes still sums correctly
  // because invalid s == 0.
}

__global__ __launch_bounds__(256) void final_k(
    const float* __restrict__ outg, const float* __restrict__ fw,
    const float* __restrict__ fb, float* __restrict__ out, int g) {
  int i = blockIdx.x * blockDim.x + threadIdx.x;
  if (i < g) out[i] = fmaf(outg[i], fw[0], fb[0]);
}

extern "C" void kernel_launch(void* const* d_in, const int* in_sizes, int n_in,
                              void* d_out, int out_size, void* d_ws, size_t ws_size,
                              hipStream_t stream) {
  const int*   z      = (const int*)d_in[0];
  const float* pos    = (const float*)d_in[1];
  const int*   batch  = (const int*)d_in[2];
  const int*   ei     = (const int*)d_in[3];
  const float* emb    = (const float*)d_in[4];
  const float* out_w1 = (const float*)d_in[5];
  const float* out_b1 = (const float*)d_in[6];
  const float* out_w2 = (const float*)d_in[7];
  const float* out_b2 = (const float*)d_in[8];
  const float* fin_w  = (const float*)d_in[9];
  const float* fin_b  = (const float*)d_in[10];
  const float* mlp_w1 = (const float*)d_in[11];
  const float* mlp_b1 = (const float*)d_in[12];
  const float* mlp_w2 = (const float*)d_in[13];
  const float* mlp_b2 = (const float*)d_in[14];
  const float* cf1    = (const float*)d_in[15];
  const float* cf2    = (const float*)d_in[16];
  const float* cf2b   = (const float*)d_in[17];
  const float* intw   = (const float*)d_in[18];
  const float* intb   = (const float*)d_in[19];

  const int N = in_sizes[0];
  const int E = in_sizes[3] / 2;
  const int G = out_size;
  const int NB = (N + 1023) / 1024;
  const int TPB = (N + 255) / 256;   // thread-per-node blocks

  char* wsb = (char*)d_ws;
  size_t off = 0;
  auto alloc = [&](size_t bytes) { char* p = wsb + off; off += (bytes + 255) & ~(size_t)255; return p; };
  float*  h    = (float*)alloc((size_t)N * HIDC * sizeof(float));
  float*  x    = (float*)alloc((size_t)N * HIDC * sizeof(float));   // aliased: also t-buffer
  float*  agg  = (float*)alloc((size_t)N * HIDC * sizeof(float));
  float2* tab2 = (float2*)alloc((size_t)NLAYER * TGRID * HIDC * sizeof(float2));
  int2*   er   = (int2*)alloc((size_t)E * sizeof(int2));
  int*    rs   = (int*)alloc((size_t)(N + 1) * sizeof(int));
  float*  outg = (float*)alloc((size_t)G * sizeof(float));
  // preprocessing-only aliases:
  int* deg    = (int*)agg;          // agg fully rewritten by gather later
  int* cursor = (int*)agg + N;
  int* bsum   = (int*)agg + 2 * N;
  float* tab  = (float*)er;         // plain table dead before er is written

  build_table_k<<<dim3(NLAYER * TGRID), dim3(64), 0, stream>>>(
      mlp_w1, mlp_b1, mlp_w2, mlp_b2, tab);
  interleave_k<<<dim3((NLAYER * TGRID * HIDC + 255) / 256), dim3(256), 0, stream>>>(
      tab, tab2, NLAYER * TGRID * HIDC);
  hipMemsetAsync(deg, 0, (size_t)N * sizeof(int), stream);
  hipMemsetAsync(outg, 0, (size_t)G * sizeof(float), stream);
  hist_k<<<dim3((E + 255) / 256), dim3(256), 0, stream>>>(ei + E, deg, E);
  scanA_k<<<dim3(NB), dim3(256), 0, stream>>>(deg, rs, bsum, N);
  scanB_k<<<dim3(1), dim3(64), 0, stream>>>(bsum, NB);
  scanC_k<<<dim3((N + 255) / 256), dim3(256), 0, stream>>>(bsum, deg, rs, cursor, N);
  scatter_k<<<dim3((E + 255) / 256), dim3(256), 0, stream>>>(ei, pos, cursor, er, E);
  init_h_k<<<dim3((N * HIDC + 255) / 256), dim3(256), 0, stream>>>(z, emb, h, N * HIDC);

  const int gather_blocks = (N + 3) / 4;   // one wave per node
  for (int l = 0; l < NLAYER; ++l) {
    node_lin_k<<<dim3(TPB), dim3(256), 0, stream>>>(
        h, cf1 + (size_t)l * HIDC * HIDC, x, N);
    gather_k<<<dim3(gather_blocks), dim3(256), 0, stream>>>(
        rs, er, tab2 + (size_t)l * TGRID * HIDC, x, agg, N);
    update1_k<<<dim3(TPB), dim3(256), 0, stream>>>(
        agg, cf2 + (size_t)l * HIDC * HIDC, cf2b + l * HIDC, x, N);  // x as t
    update2_k<<<dim3(TPB), dim3(256), 0, stream>>>(
        x, intw + (size_t)l * HIDC * HIDC, intb + l * HIDC, h, N);
  }

  out_kernel_k<<<dim3(TPB), dim3(256), 0, stream>>>(
      h, batch, out_w1, out_b1, out_w2, out_b2, outg, N);
  final_k<<<dim3((G + 255) / 256), dim3(256), 0, stream>>>(
      outg, fin_w, fin_b, (float*)d_out, G);
}

// Round 5
// 1127.334 us; speedup vs baseline: 2.4355x; 1.1013x over previous
//
#include <hip/hip_runtime.h>
#include <hip/hip_fp16.h>
#include <cstdint>
#include <cstddef>

#define HIDC   64
#define NGAUSS 50
#define NLAYER 3
#define TGRID  4096
#define CUTOFF_F 10.0f
#define LOG2_C 0.69314718055994530942f

__device__ __forceinline__ float sspf(float v) {
  return fmaxf(v, 0.0f) + log1pf(expf(-fabsf(v))) - LOG2_C;
}

// ---------------------------------------------------------------------------
// Per-layer lookup tables T_l(g,j) = [ssp(rbf(d)@w1+b1)@w2+b2]_j * C(d)
// ---------------------------------------------------------------------------
__global__ __launch_bounds__(64) void build_table_k(
    const float* __restrict__ mlp_w1, const float* __restrict__ mlp_b1,
    const float* __restrict__ mlp_w2, const float* __restrict__ mlp_b2,
    float* __restrict__ table) {
  int pid = blockIdx.x;              // l*TGRID + g
  int l = pid / TGRID;
  int g = pid - l * TGRID;
  int j = threadIdx.x;
  float d = (float)g * (CUTOFF_F / (float)(TGRID - 1));
  __shared__ float rbf_s[NGAUSS];
  __shared__ float hid_s[HIDC];
  const float delta = CUTOFF_F / (float)(NGAUSS - 1);
  const float coeff = -0.5f / (delta * delta);
  if (j < NGAUSS) {
    float t = d - (float)j * delta;
    rbf_s[j] = expf(coeff * t * t);
  }
  __syncthreads();
  const float* w1 = mlp_w1 + (size_t)l * NGAUSS * HIDC;
  float acc = mlp_b1[l * HIDC + j];
#pragma unroll
  for (int k = 0; k < NGAUSS; ++k) acc = fmaf(rbf_s[k], w1[k * HIDC + j], acc);
  hid_s[j] = sspf(acc);
  __syncthreads();
  const float* w2 = mlp_w2 + (size_t)l * HIDC * HIDC;
  float acc2 = mlp_b2[l * HIDC + j];
#pragma unroll
  for (int m = 0; m < HIDC; ++m) acc2 = fmaf(hid_s[m], w2[m * HIDC + j], acc2);
  float C = 0.5f * (cosf(d * (3.14159265358979323846f / CUTOFF_F)) + 1.0f);
  table[(size_t)pid * HIDC + j] = acc2 * C;
}

// tab2h[l][g][j] = half2(T[g][j], T[g+1][j]) — both lerp endpoints in 4B
__global__ __launch_bounds__(256) void interleave_k(
    const float* __restrict__ tab, __half2* __restrict__ tab2h, int total) {
  int idx = blockIdx.x * blockDim.x + threadIdx.x;
  if (idx >= total) return;
  int rem = idx % (TGRID * HIDC);
  int g = rem / HIDC;
  float a = tab[idx];
  float c = (g < TGRID - 1) ? tab[idx + HIDC] : a;
  tab2h[idx] = __floats2half2_rn(a, c);
}

// ---------------------------------------------------------------------------
// CSR build
// ---------------------------------------------------------------------------
__global__ __launch_bounds__(256) void hist_k(
    const int* __restrict__ edst, int* __restrict__ deg, int E) {
  int e = blockIdx.x * blockDim.x + threadIdx.x;
  if (e < E) atomicAdd(&deg[edst[e]], 1);
}

__global__ __launch_bounds__(256) void scanA_k(
    const int* __restrict__ deg, int* __restrict__ rs,
    int* __restrict__ bsum, int N) {
  __shared__ int sbuf[2][256];
  int tid = threadIdx.x;
  int base = blockIdx.x * 1024 + tid * 4;
  int v0 = (base + 0 < N) ? deg[base + 0] : 0;
  int v1 = (base + 1 < N) ? deg[base + 1] : 0;
  int v2 = (base + 2 < N) ? deg[base + 2] : 0;
  int v3 = (base + 3 < N) ? deg[base + 3] : 0;
  int p0 = v0, p1 = p0 + v1, p2 = p1 + v2, p3 = p2 + v3;
  int pout = 0;
  sbuf[0][tid] = p3;
  __syncthreads();
  for (int off = 1; off < 256; off <<= 1) {
    int pin = pout; pout ^= 1;
    int v = sbuf[pin][tid];
    if (tid >= off) v += sbuf[pin][tid - off];
    sbuf[pout][tid] = v;
    __syncthreads();
  }
  int texc = sbuf[pout][tid] - p3;
  if (base + 0 < N) rs[1 + base + 0] = texc + p0;
  if (base + 1 < N) rs[1 + base + 1] = texc + p1;
  if (base + 2 < N) rs[1 + base + 2] = texc + p2;
  if (base + 3 < N) rs[1 + base + 3] = texc + p3;
  if (tid == 255) bsum[blockIdx.x] = sbuf[pout][255];
}

__global__ void scanB_k(int* __restrict__ bsum, int nb) {
  if (threadIdx.x == 0 && blockIdx.x == 0) {
    int acc = 0;
    for (int i = 0; i < nb; ++i) { int v = bsum[i]; bsum[i] = acc; acc += v; }
  }
}

__global__ __launch_bounds__(256) void scanC_k(
    const int* __restrict__ bsum, const int* __restrict__ deg,
    int* __restrict__ rs, int* __restrict__ cursor, int N) {
  int i = blockIdx.x * blockDim.x + threadIdx.x;
  if (i < N) {
    int inc = rs[1 + i] + bsum[i >> 10];
    rs[1 + i] = inc;
    cursor[i] = inc - deg[i];
  }
  if (i == 0) rs[0] = 0;
}

// per edge: d -> (i0, f). Pack (src, i0<<16|f_q16) at cursor[dst]++ via
// nontemporal 8B store (random positions — avoid L2 write-allocate churn).
__global__ __launch_bounds__(256) void scatter_k(
    const int* __restrict__ ei, const float* __restrict__ pos,
    int* __restrict__ cursor, long long* __restrict__ er, int E) {
  int e = blockIdx.x * blockDim.x + threadIdx.x;
  if (e >= E) return;
  int s = ei[e], t = ei[E + e];
  float dx = pos[3 * s + 0] - pos[3 * t + 0];
  float dy = pos[3 * s + 1] - pos[3 * t + 1];
  float dz = pos[3 * s + 2] - pos[3 * t + 2];
  float d = sqrtf(fmaf(dx, dx, fmaf(dy, dy, dz * dz)));
  float u = d * ((float)(TGRID - 1) / CUTOFF_F);
  int i0 = (int)u;
  if (i0 > TGRID - 2) i0 = TGRID - 2;
  int fq = (int)((u - (float)i0) * 65536.0f);
  if (fq > 65535) fq = 65535;
  int pack = (i0 << 16) | fq;
  int p = atomicAdd(&cursor[t], 1);
  long long rec = (long long)((unsigned long long)(unsigned)s |
                              ((unsigned long long)(unsigned)pack << 32));
  __builtin_nontemporal_store(rec, er + p);
}

// h = emb[z]
__global__ __launch_bounds__(256) void init_h_k(
    const int* __restrict__ z, const float* __restrict__ emb,
    float* __restrict__ h, int n64) {
  int i = blockIdx.x * blockDim.x + threadIdx.x;
  if (i >= n64) return;
  h[i] = emb[(z[i >> 6] << 6) | (i & 63)];
}

// ---------------------------------------------------------------------------
// Thread-per-node 64x64 GEMMs (weights via wave-uniform s_load)
// ---------------------------------------------------------------------------

// x = half(h @ W) (no bias), fp16 output for the gather
__global__ __launch_bounds__(256) void node_lin_k(
    const float* __restrict__ h, const float* __restrict__ W,
    __half* __restrict__ x, int n) {
  int node = blockIdx.x * 256 + threadIdx.x;
  if (node >= n) return;
  const float* row = h + ((size_t)node << 6);
  float acc[HIDC];
#pragma unroll
  for (int j = 0; j < HIDC; ++j) acc[j] = 0.0f;
  for (int k = 0; k < HIDC; k += 4) {
    float4 rv = *(const float4*)(row + k);
    const float* w0 = W + (k + 0) * HIDC;
    const float* w1 = W + (k + 1) * HIDC;
    const float* w2 = W + (k + 2) * HIDC;
    const float* w3 = W + (k + 3) * HIDC;
#pragma unroll
    for (int j = 0; j < HIDC; ++j) {
      acc[j] = fmaf(rv.x, w0[j], acc[j]);
      acc[j] = fmaf(rv.y, w1[j], acc[j]);
      acc[j] = fmaf(rv.z, w2[j], acc[j]);
      acc[j] = fmaf(rv.w, w3[j], acc[j]);
    }
  }
  __half2* xr = (__half2*)(x + ((size_t)node << 6));
#pragma unroll
  for (int j = 0; j < HIDC; j += 2)
    xr[j >> 1] = __floats2half2_rn(acc[j], acc[j + 1]);
}

// h += ssp(agg @ W2 + b2) @ W3 + b3   (fused; t lives in registers)
__global__ __launch_bounds__(256) void update12_k(
    const float* __restrict__ agg,
    const float* __restrict__ W2, const float* __restrict__ b2,
    const float* __restrict__ W3, const float* __restrict__ b3,
    float* __restrict__ h, int n) {
  int node = blockIdx.x * 256 + threadIdx.x;
  if (node >= n) return;
  const float* row = agg + ((size_t)node << 6);
  float acc[HIDC];
#pragma unroll
  for (int j = 0; j < HIDC; ++j) acc[j] = b2[j];
  for (int k = 0; k < HIDC; k += 4) {
    float4 rv = *(const float4*)(row + k);
    const float* w0 = W2 + (k + 0) * HIDC;
    const float* w1 = W2 + (k + 1) * HIDC;
    const float* w2 = W2 + (k + 2) * HIDC;
    const float* w3 = W2 + (k + 3) * HIDC;
#pragma unroll
    for (int j = 0; j < HIDC; ++j) {
      acc[j] = fmaf(rv.x, w0[j], acc[j]);
      acc[j] = fmaf(rv.y, w1[j], acc[j]);
      acc[j] = fmaf(rv.z, w2[j], acc[j]);
      acc[j] = fmaf(rv.w, w3[j], acc[j]);
    }
  }
#pragma unroll
  for (int j = 0; j < HIDC; ++j) acc[j] = sspf(acc[j]);
  float acc2[HIDC];
#pragma unroll
  for (int j = 0; j < HIDC; ++j) acc2[j] = b3[j];
  for (int k = 0; k < HIDC; k += 4) {
    const float* w0 = W3 + (k + 0) * HIDC;
    const float* w1 = W3 + (k + 1) * HIDC;
    const float* w2 = W3 + (k + 2) * HIDC;
    const float* w3 = W3 + (k + 3) * HIDC;
    float t0 = acc[k + 0], t1 = acc[k + 1], t2 = acc[k + 2], t3 = acc[k + 3];
#pragma unroll
    for (int j = 0; j < HIDC; ++j) {
      acc2[j] = fmaf(t0, w0[j], acc2[j]);
      acc2[j] = fmaf(t1, w1[j], acc2[j]);
      acc2[j] = fmaf(t2, w2[j], acc2[j]);
      acc2[j] = fmaf(t3, w3[j], acc2[j]);
    }
  }
  float* hr = h + ((size_t)node << 6);
#pragma unroll
  for (int j = 0; j < HIDC; j += 4) {
    float4 hv = *(float4*)(hr + j);
    hv.x += acc2[j]; hv.y += acc2[j + 1];
    hv.z += acc2[j + 2]; hv.w += acc2[j + 3];
    *(float4*)(hr + j) = hv;
  }
}

// THE HOT KERNEL. One wave per dst node, edge loop unrolled x4.
// fp16 table (half2 lerp endpoints, 4B/lane) + fp16 x (2B/lane).
__global__ __launch_bounds__(256) void gather_k(
    const int* __restrict__ rs, const int2* __restrict__ er,
    const __half2* __restrict__ tab2h, const __half* __restrict__ x,
    float* __restrict__ agg, int n) {
  int j = threadIdx.x & 63;
  int node = (blockIdx.x * 256 + threadIdx.x) >> 6;
  if (node >= n) return;
  int beg = __builtin_amdgcn_readfirstlane(rs[node]);
  int end = __builtin_amdgcn_readfirstlane(rs[node + 1]);
  float acc = 0.0f;
  int k = beg;
  for (; k + 4 <= end; k += 4) {
    int2 r0 = er[k + 0];
    int2 r1 = er[k + 1];
    int2 r2 = er[k + 2];
    int2 r3 = er[k + 3];
    __half2 h0 = tab2h[((size_t)(r0.y >> 16) << 6) + j];
    __half2 h1 = tab2h[((size_t)(r1.y >> 16) << 6) + j];
    __half2 h2 = tab2h[((size_t)(r2.y >> 16) << 6) + j];
    __half2 h3 = tab2h[((size_t)(r3.y >> 16) << 6) + j];
    float x0 = __half2float(x[((size_t)r0.x << 6) + j]);
    float x1 = __half2float(x[((size_t)r1.x << 6) + j]);
    float x2 = __half2float(x[((size_t)r2.x << 6) + j]);
    float x3 = __half2float(x[((size_t)r3.x << 6) + j]);
    float2 a0 = __half22float2(h0);
    float2 a1 = __half22float2(h1);
    float2 a2 = __half22float2(h2);
    float2 a3 = __half22float2(h3);
    float f0 = (float)(r0.y & 0xffff) * (1.0f / 65536.0f);
    float f1 = (float)(r1.y & 0xffff) * (1.0f / 65536.0f);
    float f2 = (float)(r2.y & 0xffff) * (1.0f / 65536.0f);
    float f3 = (float)(r3.y & 0xffff) * (1.0f / 65536.0f);
    acc = fmaf(x0, fmaf(f0, a0.y - a0.x, a0.x), acc);
    acc = fmaf(x1, fmaf(f1, a1.y - a1.x, a1.x), acc);
    acc = fmaf(x2, fmaf(f2, a2.y - a2.x, a2.x), acc);
    acc = fmaf(x3, fmaf(f3, a3.y - a3.x, a3.x), acc);
  }
  for (; k < end; ++k) {
    int2 r = er[k];
    float2 a = __half22float2(tab2h[((size_t)(r.y >> 16) << 6) + j]);
    float f = (float)(r.y & 0xffff) * (1.0f / 65536.0f);
    acc = fmaf(__half2float(x[((size_t)r.x << 6) + j]),
               fmaf(f, a.y - a.x, a.x), acc);
  }
  agg[((size_t)node << 6) + j] = acc;
}

// per-atom output MLP + segmented wave reduce (batch sorted) + atomic
__global__ __launch_bounds__(256) void out_kernel_k(
    const float* __restrict__ h, const int* __restrict__ batch,
    const float* __restrict__ ow1, const float* __restrict__ ob1,
    const float* __restrict__ ow2, const float* __restrict__ ob2,
    float* __restrict__ outg, int n) {
  int node = blockIdx.x * 256 + threadIdx.x;
  int lane = threadIdx.x & 63;
  bool valid = node < n;
  int b = batch[valid ? node : (n - 1)];
  float s = 0.0f;
  if (valid) {
    const float* row = h + ((size_t)node << 6);
    float acc[32];
#pragma unroll
    for (int j = 0; j < 32; ++j) acc[j] = ob1[j];
    for (int k = 0; k < HIDC; k += 4) {
      float4 rv = *(const float4*)(row + k);
      const float* w0 = ow1 + (k + 0) * 32;
      const float* w1 = ow1 + (k + 1) * 32;
      const float* w2 = ow1 + (k + 2) * 32;
      const float* w3 = ow1 + (k + 3) * 32;
#pragma unroll
      for (int j = 0; j < 32; ++j) {
        acc[j] = fmaf(rv.x, w0[j], acc[j]);
        acc[j] = fmaf(rv.y, w1[j], acc[j]);
        acc[j] = fmaf(rv.z, w2[j], acc[j]);
        acc[j] = fmaf(rv.w, w3[j], acc[j]);
      }
    }
    s = ob2[0];
#pragma unroll
    for (int j = 0; j < 32; ++j) s = fmaf(sspf(acc[j]), ow2[j], s);
  }
  // segmented suffix sum over contiguous equal-b runs (batch sorted)
#pragma unroll
  for (int off = 1; off < 64; off <<= 1) {
    float so = __shfl_down(s, off);
    int bo = __shfl_down(b, off);
    if (lane + off < 64 && bo == b) s += so;
  }
  int bprev = __shfl_up(b, 1);
  bool head = (lane == 0) || (bprev != b);
  if (head && valid) unsafeAtomicAdd(&outg[b], s);
}

__global__ __launch_bounds__(256) void final_k(
    const float* __restrict__ outg, const float* __restrict__ fw,
    const float* __restrict__ fb, float* __restrict__ out, int g) {
  int i = blockIdx.x * blockDim.x + threadIdx.x;
  if (i < g) out[i] = fmaf(outg[i], fw[0], fb[0]);
}

extern "C" void kernel_launch(void* const* d_in, const int* in_sizes, int n_in,
                              void* d_out, int out_size, void* d_ws, size_t ws_size,
                              hipStream_t stream) {
  const int*   z      = (const int*)d_in[0];
  const float* pos    = (const float*)d_in[1];
  const int*   batch  = (const int*)d_in[2];
  const int*   ei     = (const int*)d_in[3];
  const float* emb    = (const float*)d_in[4];
  const float* out_w1 = (const float*)d_in[5];
  const float* out_b1 = (const float*)d_in[6];
  const float* out_w2 = (const float*)d_in[7];
  const float* out_b2 = (const float*)d_in[8];
  const float* fin_w  = (const float*)d_in[9];
  const float* fin_b  = (const float*)d_in[10];
  const float* mlp_w1 = (const float*)d_in[11];
  const float* mlp_b1 = (const float*)d_in[12];
  const float* mlp_w2 = (const float*)d_in[13];
  const float* mlp_b2 = (const float*)d_in[14];
  const float* cf1    = (const float*)d_in[15];
  const float* cf2    = (const float*)d_in[16];
  const float* cf2b   = (const float*)d_in[17];
  const float* intw   = (const float*)d_in[18];
  const float* intb   = (const float*)d_in[19];

  const int N = in_sizes[0];
  const int E = in_sizes[3] / 2;
  const int G = out_size;
  const int NB = (N + 1023) / 1024;
  const int TPB = (N + 255) / 256;   // thread-per-node blocks

  char* wsb = (char*)d_ws;
  size_t off = 0;
  auto alloc = [&](size_t bytes) { char* p = wsb + off; off += (bytes + 255) & ~(size_t)255; return p; };
  float*   h     = (float*)alloc((size_t)N * HIDC * sizeof(float));
  __half*  x     = (__half*)alloc((size_t)N * HIDC * sizeof(__half));
  float*   agg   = (float*)alloc((size_t)N * HIDC * sizeof(float));
  __half2* tab2h = (__half2*)alloc((size_t)NLAYER * TGRID * HIDC * sizeof(__half2));
  int2*    er    = (int2*)alloc((size_t)E * sizeof(int2));
  int*     rs    = (int*)alloc((size_t)(N + 1) * sizeof(int));
  float*   outg  = (float*)alloc((size_t)G * sizeof(float));
  float*   tab   = (float*)alloc((size_t)NLAYER * TGRID * HIDC * sizeof(float));
  // preprocessing-only aliases (agg fully rewritten by gather before use):
  int* deg    = (int*)agg;
  int* cursor = (int*)agg + N;
  int* bsum   = (int*)agg + 2 * N;

  build_table_k<<<dim3(NLAYER * TGRID), dim3(64), 0, stream>>>(
      mlp_w1, mlp_b1, mlp_w2, mlp_b2, tab);
  interleave_k<<<dim3((NLAYER * TGRID * HIDC + 255) / 256), dim3(256), 0, stream>>>(
      tab, tab2h, NLAYER * TGRID * HIDC);
  hipMemsetAsync(deg, 0, (size_t)N * sizeof(int), stream);
  hipMemsetAsync(outg, 0, (size_t)G * sizeof(float), stream);
  hist_k<<<dim3((E + 255) / 256), dim3(256), 0, stream>>>(ei + E, deg, E);
  scanA_k<<<dim3(NB), dim3(256), 0, stream>>>(deg, rs, bsum, N);
  scanB_k<<<dim3(1), dim3(64), 0, stream>>>(bsum, NB);
  scanC_k<<<dim3((N + 255) / 256), dim3(256), 0, stream>>>(bsum, deg, rs, cursor, N);
  scatter_k<<<dim3((E + 255) / 256), dim3(256), 0, stream>>>(
      ei, pos, cursor, (long long*)er, E);
  init_h_k<<<dim3((N * HIDC + 255) / 256), dim3(256), 0, stream>>>(z, emb, h, N * HIDC);

  const int gather_blocks = (N + 3) / 4;   // one wave per node
  for (int l = 0; l < NLAYER; ++l) {
    node_lin_k<<<dim3(TPB), dim3(256), 0, stream>>>(
        h, cf1 + (size_t)l * HIDC * HIDC, x, N);
    gather_k<<<dim3(gather_blocks), dim3(256), 0, stream>>>(
        rs, er, tab2h + (size_t)l * TGRID * HIDC, x, agg, N);
    update12_k<<<dim3(TPB), dim3(256), 0, stream>>>(
        agg, cf2 + (size_t)l * HIDC * HIDC, cf2b + l * HIDC,
        intw + (size_t)l * HIDC * HIDC, intb + l * HIDC, h, N);
  }

  out_kernel_k<<<dim3(TPB), dim3(256), 0, stream>>>(
      h, batch, out_w1, out_b1, out_w2, out_b2, outg, N);
  final_k<<<dim3((G + 255) / 256), dim3(256), 0, stream>>>(
      outg, fin_w, fin_b, (float*)d_out, G);
}